// Round 1
// baseline (135.125 us; speedup 1.0000x reference)
//
#include <hip/hip_runtime.h>
#include <hip/hip_bf16.h>
#include <stdint.h>

// Problem constants
#define HH 64
#define WW 64
#define NB 4
#define CIN_ 256
#define COUT_ 256
#define DG_ 4
#define KK_ 9

typedef __attribute__((ext_vector_type(8))) short bf16x8;
typedef __attribute__((ext_vector_type(4))) float f32x4;
typedef __attribute__((ext_vector_type(4))) unsigned int u32x4;

__device__ __forceinline__ float b2f(unsigned int u16) {
  union { unsigned int i; float f; } c; c.i = u16 << 16; return c.f;
}
__device__ __forceinline__ unsigned int f2b(float f) {
  union { float f; unsigned int i; } c; c.f = f;
  unsigned int x = c.i;
  return (x + 0x7fffu + ((x >> 16) & 1u)) >> 16;  // RNE
}

// ---------------- kernel 1: offset conv (B,2,64,64) -> (B,72,64,64) ----------------
__global__ __launch_bounds__(256) void k_offset_conv(
    const float* __restrict__ shape, const float* __restrict__ w_off,
    float* __restrict__ offset) {
  int bid = blockIdx.x;            // b*72 + oc, 288 blocks
  int b = bid / 72, oc = bid % 72;
  float wv[18];
#pragma unroll
  for (int i = 0; i < 18; ++i) wv[i] = w_off[oc * 18 + i];
  const float* sp = shape + (size_t)b * 2 * 4096;
  float* op = offset + (size_t)bid * 4096;
  for (int p = threadIdx.x; p < 4096; p += 256) {
    int y = p >> 6, x = p & 63;
    float acc = 0.f;
#pragma unroll
    for (int ic = 0; ic < 2; ++ic)
#pragma unroll
      for (int ky = 0; ky < 3; ++ky) {
        int yy = y + ky - 1;
        if (yy < 0 || yy > 63) continue;
#pragma unroll
        for (int kx = 0; kx < 3; ++kx) {
          int xx = x + kx - 1;
          if (xx < 0 || xx > 63) continue;
          acc += sp[ic * 4096 + yy * 64 + xx] * wv[ic * 9 + ky * 3 + kx];
        }
      }
    op[p] = acc;
  }
}

// ---------------- kernel 2: transpose x (B,C,H,W) f32 -> x_t (B,H,W,C) bf16 ----------------
__global__ __launch_bounds__(256) void k_transpose(
    const float* __restrict__ x, __hip_bfloat16* __restrict__ xt) {
  __shared__ float tile[64][65];
  int bid = blockIdx.x;                 // 1024 = 4 * 4 * 64
  int b = bid >> 8, ct = (bid >> 6) & 3, pt = bid & 63;
  int t = threadIdx.x;
  int c0 = ct * 64, p0 = pt * 64;
#pragma unroll
  for (int i = 0; i < 16; ++i) {
    int cl = (t >> 6) * 16 + i;
    int pl = t & 63;
    tile[cl][pl] = x[(size_t)(b * 256 + c0 + cl) * 4096 + p0 + pl];
  }
  __syncthreads();
#pragma unroll
  for (int i = 0; i < 16; ++i) {
    int pl = (t >> 6) * 16 + i;
    int cl = t & 63;
    xt[(size_t)(b * 4096 + p0 + pl) * 256 + c0 + cl] = __float2bfloat16(tile[cl][pl]);
  }
}

// ---------------- kernel 3: pack weights into pre-swizzled LDS image ----------------
// w_pack[chunk][m][cs] bf16, chunk = kk*4+g, cs = c ^ ((m&7)<<3)  (16B-slot XOR swizzle)
// holds w_deform[m][g*64+c][kk]
__global__ __launch_bounds__(256) void k_pack_w(
    const float* __restrict__ wd, __hip_bfloat16* __restrict__ wp) {
  int idx = blockIdx.x * 256 + threadIdx.x;   // 2304 blocks -> 589824
  int chunk = idx >> 14;
  int m = (idx >> 6) & 255;
  int cs = idx & 63;
  int c = cs ^ ((m & 7) << 3);
  int kk = chunk >> 2, g = chunk & 3;
  wp[idx] = __float2bfloat16(wd[(size_t)(m * 256 + g * 64 + c) * 9 + kk]);
}

// ---------------- kernel 4: fused deformable conv (sampling + MFMA GEMM + ReLU) ----------------
// grid 512: block = (b, y, mb); tile M=128 (couts mb*128..+127) x N=64 (row y), K-chunks of 64
__global__ __launch_bounds__(256, 2) void k_deform_main(
    const __hip_bfloat16* __restrict__ xt, const __hip_bfloat16* __restrict__ wp,
    const float* __restrict__ offs, float* __restrict__ out) {
  __shared__ __align__(16) char lds[24576];   // A: 16KB (128x64 bf16), B: 8KB (64x64 bf16)
  const int t = threadIdx.x;
  const int l = t & 63;
  const int wid = t >> 6;

  // XCD-aware chunked swizzle (512 % 8 == 0, bijective)
  int orig = blockIdx.x;
  int bid = (orig & 7) * 64 + (orig >> 3);
  const int mb = bid & 1;
  const int rowid = bid >> 1;        // 0..255
  const int b = rowid >> 6;
  const int y = rowid & 63;

  const int xc = t & 63;             // sampling x position
  const int cg = t >> 6;             // 16-channel subgroup

  f32x4 acc[2][4] = {};
  const float* offb = offs + (size_t)b * 72 * 4096 + y * 64 + xc;
  const __hip_bfloat16* xtb = xt + (size_t)b * 4096 * 256;
  const int swz = (l & 7) << 4;

  for (int chunk = 0; chunk < 36; ++chunk) {
    const int kk = chunk >> 2, g = chunk & 3;
    const int ky = kk / 3, kx = kk - ky * 3;

    // ---- stage A chunk (16KB, linear copy; image is pre-swizzled) ----
    {
      const __hip_bfloat16* asrc = wp + chunk * 16384 + mb * 8192 + wid * 2048 + l * 8;
      char* adst = lds + wid * 4096;
#pragma unroll
      for (int i = 0; i < 4; ++i) {
        __builtin_amdgcn_global_load_lds(
            (const __attribute__((address_space(1))) unsigned int*)(asrc + i * 512),
            (__attribute__((address_space(3))) unsigned int*)(adst + i * 1024),
            16, 0, 0);
      }
    }

    // ---- build B tile: bilinear sampling of 16 channels at position xc ----
    {
      float dy = offb[(size_t)(g * 18 + kk * 2) * 4096];
      float dx = offb[(size_t)(g * 18 + kk * 2 + 1) * 4096];
      float sy = dy + (float)(y + ky - 1);
      float sx = dx + (float)(xc + kx - 1);
      float fy = floorf(sy), fx = floorf(sx);
      float ly = sy - fy, lx = sx - fx;
      int y0 = (int)fy, x0 = (int)fx;
      float m00 = (y0 >= 0 && y0 <= 63 && x0 >= 0 && x0 <= 63) ? 1.f : 0.f;
      float m01 = (y0 >= 0 && y0 <= 63 && x0 >= -1 && x0 <= 62) ? 1.f : 0.f;
      float m10 = (y0 >= -1 && y0 <= 62 && x0 >= 0 && x0 <= 63) ? 1.f : 0.f;
      float m11 = (y0 >= -1 && y0 <= 62 && x0 >= -1 && x0 <= 62) ? 1.f : 0.f;
      float cw[4];
      cw[0] = (1.f - ly) * (1.f - lx) * m00;
      cw[1] = (1.f - ly) * lx * m01;
      cw[2] = ly * (1.f - lx) * m10;
      cw[3] = ly * lx * m11;
      int yc0 = min(max(y0, 0), 63), yc1 = min(max(y0 + 1, 0), 63);
      int xc0 = min(max(x0, 0), 63), xc1 = min(max(x0 + 1, 0), 63);
      const int cb = g * 64 + cg * 16;
      const __hip_bfloat16* cp[4];
      cp[0] = xtb + ((yc0 * 64 + xc0) * 256 + cb);
      cp[1] = xtb + ((yc0 * 64 + xc1) * 256 + cb);
      cp[2] = xtb + ((yc1 * 64 + xc0) * 256 + cb);
      cp[3] = xtb + ((yc1 * 64 + xc1) * 256 + cb);
      u32x4 cv[4][2];
#pragma unroll
      for (int c = 0; c < 4; ++c) {
        cv[c][0] = *(const u32x4*)(cp[c]);
        cv[c][1] = *(const u32x4*)(cp[c] + 8);
      }
      u32x4 o0, o1;
#pragma unroll
      for (int h = 0; h < 2; ++h) {
#pragma unroll
        for (int wq = 0; wq < 4; ++wq) {
          float lo = 0.f, hi = 0.f;
#pragma unroll
          for (int c = 0; c < 4; ++c) {
            unsigned int wv = cv[c][h][wq];
            lo += cw[c] * b2f(wv & 0xffffu);
            hi += cw[c] * b2f(wv >> 16);
          }
          unsigned int pw = f2b(lo) | (f2b(hi) << 16);
          if (h == 0) o0[wq] = pw; else o1[wq] = pw;
        }
      }
      char* bbase = lds + 16384 + xc * 128;
      *(u32x4*)(bbase + ((cg * 32) ^ ((xc & 7) << 4))) = o0;
      *(u32x4*)(bbase + ((cg * 32 + 16) ^ ((xc & 7) << 4))) = o1;
    }
    __syncthreads();   // drains vmcnt (global_load_lds) + lgkmcnt (ds_writes)

    // ---- MFMA: wave tile 32x64, two K=32 steps ----
    {
      const int lm = l & 15;
      const int kq = (l >> 4) << 4;  // byte offset of this lane's 16B k-slot
#pragma unroll
      for (int ks = 0; ks < 2; ++ks) {
        const int kb = ks * 64 + kq;
        bf16x8 a0 = *(const bf16x8*)(lds + (wid * 32 + lm) * 128 + (kb ^ swz));
        bf16x8 a1 = *(const bf16x8*)(lds + (wid * 32 + 16 + lm) * 128 + (kb ^ swz));
#pragma unroll
        for (int j = 0; j < 4; ++j) {
          bf16x8 bj = *(const bf16x8*)(lds + 16384 + (j * 16 + lm) * 128 + (kb ^ swz));
          acc[0][j] = __builtin_amdgcn_mfma_f32_16x16x32_bf16(a0, bj, acc[0][j], 0, 0, 0);
          acc[1][j] = __builtin_amdgcn_mfma_f32_16x16x32_bf16(a1, bj, acc[1][j], 0, 0, 0);
        }
      }
    }
    __syncthreads();
  }

  // ---- epilogue: ReLU + store fp32 ----
  const int lm4 = (l >> 4) << 2;
  float* ob = out + ((size_t)(b * 256 + mb * 128 + wid * 32)) * 4096 + y * 64;
#pragma unroll
  for (int i = 0; i < 2; ++i)
#pragma unroll
    for (int j = 0; j < 4; ++j)
#pragma unroll
      for (int r = 0; r < 4; ++r) {
        int m = i * 16 + lm4 + r;
        ob[(size_t)m * 4096 + j * 16 + (l & 15)] = fmaxf(acc[i][j][r], 0.f);
      }
}

extern "C" void kernel_launch(void* const* d_in, const int* in_sizes, int n_in,
                              void* d_out, int out_size, void* d_ws, size_t ws_size,
                              hipStream_t stream) {
  const float* x      = (const float*)d_in[0];
  const float* shape  = (const float*)d_in[1];
  const float* w_off  = (const float*)d_in[2];
  const float* w_def  = (const float*)d_in[3];
  float* out = (float*)d_out;
  char* ws = (char*)d_ws;

  float* offset        = (float*)ws;                            // 4,718,592 B
  __hip_bfloat16* xt   = (__hip_bfloat16*)(ws + 4718592);       // 8,388,608 B
  __hip_bfloat16* wpk  = (__hip_bfloat16*)(ws + 4718592 + 8388608); // 1,179,648 B

  k_offset_conv<<<288, 256, 0, stream>>>(shape, w_off, offset);
  k_transpose<<<1024, 256, 0, stream>>>(x, xt);
  k_pack_w<<<2304, 256, 0, stream>>>(w_def, wpk);
  k_deform_main<<<512, 256, 0, stream>>>(xt, wpk, offset, out);
}

// Round 2
// 100.103 us; speedup vs baseline: 1.3499x; 1.3499x over previous
//
#include <hip/hip_runtime.h>
#include <hip/hip_bf16.h>
#include <stdint.h>

typedef __attribute__((ext_vector_type(8))) short bf16x8;
typedef __attribute__((ext_vector_type(4))) float f32x4;
typedef __attribute__((ext_vector_type(4))) unsigned int u32x4;

__device__ __forceinline__ float b2f(unsigned int u16) {
  union { unsigned int i; float f; } c; c.i = u16 << 16; return c.f;
}
__device__ __forceinline__ unsigned int f2b(float f) {
  union { float f; unsigned int i; } c; c.f = f;
  unsigned int x = c.i;
  return (x + 0x7fffu + ((x >> 16) & 1u)) >> 16;  // RNE
}

// ================= prep kernel: offset conv + transpose + weight pack =================
// blocks 0..287: offset conv (B,2,64,64)->off2 float2[(b*4+g)*9+kk][4096]
// blocks 288..1311: x (B,C,H,W) f32 -> xt (B,H,W,C) bf16
// blocks 1312..1375: w_deform -> pre-swizzled bf16 LDS image
__global__ __launch_bounds__(256) void k_prep(
    const float* __restrict__ shape, const float* __restrict__ w_off,
    const float* __restrict__ x, const float* __restrict__ wd,
    float* __restrict__ off2, __hip_bfloat16* __restrict__ xt,
    __hip_bfloat16* __restrict__ wp) {
  __shared__ float tile[64][65];
  int bid = blockIdx.x;
  int t = threadIdx.x;
  if (bid < 288) {
    int b = bid / 72, oc = bid % 72;
    int g = oc / 18, rem = oc % 18, kk = rem >> 1, s = rem & 1;
    float wv[18];
#pragma unroll
    for (int i = 0; i < 18; ++i) wv[i] = w_off[oc * 18 + i];
    const float* sp = shape + (size_t)b * 2 * 4096;
    float* op = off2 + (size_t)(((b * 4 + g) * 9 + kk) * 4096) * 2 + s;
    for (int p = t; p < 4096; p += 256) {
      int y = p >> 6, xx0 = p & 63;
      float acc = 0.f;
#pragma unroll
      for (int ic = 0; ic < 2; ++ic)
#pragma unroll
        for (int ky = 0; ky < 3; ++ky) {
          int yy = y + ky - 1;
          if (yy < 0 || yy > 63) continue;
#pragma unroll
          for (int kx = 0; kx < 3; ++kx) {
            int xx = xx0 + kx - 1;
            if (xx < 0 || xx > 63) continue;
            acc += sp[ic * 4096 + yy * 64 + xx] * wv[ic * 9 + ky * 3 + kx];
          }
        }
      op[(size_t)p * 2] = acc;
    }
  } else if (bid < 1312) {
    int id = bid - 288;                 // 1024 = 4b * 4ct * 64pt
    int b = id >> 8, ct = (id >> 6) & 3, pt = id & 63;
    int c0 = ct * 64, p0 = pt * 64;
#pragma unroll
    for (int i = 0; i < 16; ++i) {
      int cl = (t >> 6) * 16 + i;
      int pl = t & 63;
      tile[cl][pl] = x[(size_t)(b * 256 + c0 + cl) * 4096 + p0 + pl];
    }
    __syncthreads();
#pragma unroll
    for (int i = 0; i < 16; ++i) {
      int pl = (t >> 6) * 16 + i;
      int cl = t & 63;
      xt[(size_t)(b * 4096 + p0 + pl) * 256 + c0 + cl] = __float2bfloat16(tile[cl][pl]);
    }
  } else {
    // pack: wp[chunk][m][cs], cs = c ^ ((m&7)<<3), holds wd[m][g*64+c][kk], chunk=kk*4+g
    int tg = (bid - 1312) * 256 + t;    // 0..16383
#pragma unroll
    for (int i = 0; i < 36; ++i) {
      int idx = tg + i * 16384;
      int chunk = idx >> 14;
      int m = (idx >> 6) & 255;
      int cs = idx & 63;
      int c = cs ^ ((m & 7) << 3);
      int kk = chunk >> 2, g = chunk & 3;
      wp[idx] = __float2bfloat16(wd[(size_t)(m * 256 + g * 64 + c) * 9 + kk]);
    }
  }
}

// ================= main fused kernel =================
// grid 1024: (b, y, xh, mb); tile M=128 x N=32, K-chunks of 64 (one (kk,g) each)
// LDS: A dbuf 2x16KB + B dbuf 2x4KB = 40KB -> 4 blocks/CU
#define ISSUE_OFFS(c, ov) do { \
    int kk_ = (c) >> 2, g_ = (c) & 3; \
    ov = *(const float2*)(off2p + (size_t)(g_ * 9 + kk_) * 8192); \
  } while (0)

#define ISSUE_CORNERS(c, ov, cv, cw) do { \
    int kk_ = (c) >> 2; \
    int ky_ = kk_ / 3, kx_ = kk_ - ky_ * 3; \
    int g_ = (c) & 3; \
    float sy = ov.x + (float)(y + ky_ - 1); \
    float sx = ov.y + (float)(xg + kx_ - 1); \
    float fy = floorf(sy), fx = floorf(sx); \
    float ly = sy - fy, lx = sx - fx; \
    int y0 = (int)fy, x0 = (int)fx; \
    float vy0 = (y0 >= 0 && y0 <= 63) ? 1.f : 0.f; \
    float vy1 = (y0 >= -1 && y0 <= 62) ? 1.f : 0.f; \
    float vx0 = (x0 >= 0 && x0 <= 63) ? 1.f : 0.f; \
    float vx1 = (x0 >= -1 && x0 <= 62) ? 1.f : 0.f; \
    cw[0] = (1.f - ly) * (1.f - lx) * vy0 * vx0; \
    cw[1] = (1.f - ly) * lx * vy0 * vx1; \
    cw[2] = ly * (1.f - lx) * vy1 * vx0; \
    cw[3] = ly * lx * vy1 * vx1; \
    int yc0 = min(max(y0, 0), 63), yc1 = min(max(y0 + 1, 0), 63); \
    int xc0 = min(max(x0, 0), 63), xc1 = min(max(x0 + 1, 0), 63); \
    const __hip_bfloat16* r0_ = xtb + yc0 * 16384 + g_ * 64 + cb; \
    const __hip_bfloat16* r1_ = xtb + yc1 * 16384 + g_ * 64 + cb; \
    cv[0] = *(const u32x4*)(r0_ + xc0 * 256); \
    cv[1] = *(const u32x4*)(r0_ + xc1 * 256); \
    cv[2] = *(const u32x4*)(r1_ + xc0 * 256); \
    cv[3] = *(const u32x4*)(r1_ + xc1 * 256); \
  } while (0)

#define BLEND_WRITE(cv, cw, bbuf) do { \
    u32x4 o_; \
    _Pragma("unroll") for (int wq = 0; wq < 4; ++wq) { \
      float lo = 0.f, hi = 0.f; \
      _Pragma("unroll") for (int cc = 0; cc < 4; ++cc) { \
        unsigned int wv = cv[cc][wq]; \
        lo += cw[cc] * b2f(wv & 0xffffu); \
        hi += cw[cc] * b2f(wv >> 16); \
      } \
      o_[wq] = f2b(lo) | (f2b(hi) << 16); \
    } \
    *(u32x4*)((bbuf) + bwr) = o_; \
  } while (0)

#define STAGE_A(c, abuf) do { \
    const __hip_bfloat16* asrc_ = wp + (c) * 16384 + mb * 8192 + wid * 2048 + l * 8; \
    _Pragma("unroll") for (int i_ = 0; i_ < 4; ++i_) \
      __builtin_amdgcn_global_load_lds( \
          (const __attribute__((address_space(1))) unsigned int*)(asrc_ + i_ * 512), \
          (__attribute__((address_space(3))) unsigned int*)((abuf) + wid * 4096 + i_ * 1024), \
          16, 0, 0); \
  } while (0)

#define MFMA_STEP(abuf, bbuf) do { \
    _Pragma("unroll") for (int ks_ = 0; ks_ < 2; ++ks_) { \
      int kb_ = ks_ * 64 + kq; \
      bf16x8 a0_ = *(const bf16x8*)((abuf) + (wid * 32 + lm) * 128 + (kb_ ^ swz)); \
      bf16x8 a1_ = *(const bf16x8*)((abuf) + (wid * 32 + 16 + lm) * 128 + (kb_ ^ swz)); \
      bf16x8 b0_ = *(const bf16x8*)((bbuf) + lm * 128 + (kb_ ^ swz)); \
      bf16x8 b1_ = *(const bf16x8*)((bbuf) + (16 + lm) * 128 + (kb_ ^ swz)); \
      acc00 = __builtin_amdgcn_mfma_f32_16x16x32_bf16(a0_, b0_, acc00, 0, 0, 0); \
      acc01 = __builtin_amdgcn_mfma_f32_16x16x32_bf16(a0_, b1_, acc01, 0, 0, 0); \
      acc10 = __builtin_amdgcn_mfma_f32_16x16x32_bf16(a1_, b0_, acc10, 0, 0, 0); \
      acc11 = __builtin_amdgcn_mfma_f32_16x16x32_bf16(a1_, b1_, acc11, 0, 0, 0); \
    } \
  } while (0)

__global__ __launch_bounds__(256, 4) void k_deform_main(
    const __hip_bfloat16* __restrict__ xt, const __hip_bfloat16* __restrict__ wp,
    const float* __restrict__ off2, float* __restrict__ out) {
  __shared__ __align__(16) char lds[40960];  // A0,A1: 16KB each; B0,B1: 4KB each
  const int t = threadIdx.x;
  const int l = t & 63;
  const int wid = t >> 6;

  // XCD-aware chunked swizzle (1024 % 8 == 0, bijective)
  int orig = blockIdx.x;
  int bid = (orig & 7) * 128 + (orig >> 3);
  const int mb = bid & 1;
  const int xh = (bid >> 1) & 1;
  const int rowid = bid >> 2;        // 0..255
  const int b = rowid >> 6;
  const int y = rowid & 63;

  // sampling map: 8 lanes per position -> coalesced 128B corner reads
  const int p = t >> 3;              // 0..31 local position
  const int cb = (t & 7) * 8;        // channel octet within group
  const int xg = xh * 32 + p;        // global x
  const int bwr = p * 128 + ((cb * 2) ^ ((p & 7) << 4));  // B LDS write byte

  const int lm = l & 15;
  const int kq = (l >> 4) << 4;
  const int swz = (lm & 7) << 4;

  f32x4 acc00 = {}, acc01 = {}, acc10 = {}, acc11 = {};

  const float* off2p = off2 + (size_t)b * 36 * 8192 + (size_t)(y * 64 + xg) * 2;
  const __hip_bfloat16* xtb = xt + (size_t)b * 4096 * 256;

  char* ldsA0 = lds;
  char* ldsA1 = lds + 16384;
  char* ldsB0 = lds + 32768;
  char* ldsB1 = lds + 36864;

  u32x4 cvX[4], cvY[4];
  float cwX[4], cwY[4];
  float2 ovX, ovY;

  // prologue: chunk 0 corners + chunk 1 offsets in flight; A[0] staging
  {
    float2 ov0;
    ISSUE_OFFS(0, ov0);
    STAGE_A(0, ldsA0);
    ISSUE_CORNERS(0, ov0, cvX, cwX);
    ISSUE_OFFS(1, ovX);
  }

  for (int pr = 0; pr < 18; ++pr) {
    const int c0 = pr * 2;
    // ---- even chunk c0: buffers 0 ----
    BLEND_WRITE(cvX, cwX, ldsB0);
    __syncthreads();                  // drains A[c0] staging + B0 writes
    STAGE_A(c0 + 1, ldsA1);
    ISSUE_CORNERS(c0 + 1, ovX, cvY, cwY);
    if (c0 + 2 < 36) ISSUE_OFFS(c0 + 2, ovY);
    MFMA_STEP(ldsA0, ldsB0);
    // ---- odd chunk c0+1: buffers 1 ----
    BLEND_WRITE(cvY, cwY, ldsB1);
    __syncthreads();                  // drains A[c0+1] staging + B1 writes
    if (c0 + 2 < 36) {
      STAGE_A(c0 + 2, ldsA0);
      ISSUE_CORNERS(c0 + 2, ovY, cvX, cwX);
    }
    if (c0 + 3 < 36) ISSUE_OFFS(c0 + 3, ovX);
    MFMA_STEP(ldsA1, ldsB1);
  }

  // ---- epilogue: ReLU + fp32 store ----
  const int lm4 = (l >> 4) << 2;
  float* ob = out + (size_t)(b * 256 + mb * 128 + wid * 32) * 4096 + y * 64 + xh * 32;
#pragma unroll
  for (int r = 0; r < 4; ++r) {
    ob[(size_t)(lm4 + r) * 4096 + lm] = fmaxf(acc00[r], 0.f);
    ob[(size_t)(lm4 + r) * 4096 + 16 + lm] = fmaxf(acc01[r], 0.f);
    ob[(size_t)(16 + lm4 + r) * 4096 + lm] = fmaxf(acc10[r], 0.f);
    ob[(size_t)(16 + lm4 + r) * 4096 + 16 + lm] = fmaxf(acc11[r], 0.f);
  }
}

extern "C" void kernel_launch(void* const* d_in, const int* in_sizes, int n_in,
                              void* d_out, int out_size, void* d_ws, size_t ws_size,
                              hipStream_t stream) {
  const float* x     = (const float*)d_in[0];
  const float* shape = (const float*)d_in[1];
  const float* w_off = (const float*)d_in[2];
  const float* w_def = (const float*)d_in[3];
  float* out = (float*)d_out;
  char* ws = (char*)d_ws;

  float* off2         = (float*)ws;                                  // 4,718,592 B
  __hip_bfloat16* xt  = (__hip_bfloat16*)(ws + 4718592);             // 8,388,608 B
  __hip_bfloat16* wpk = (__hip_bfloat16*)(ws + 4718592 + 8388608);   // 1,179,648 B

  k_prep<<<1376, 256, 0, stream>>>(shape, w_off, x, w_def, off2, xt, wpk);
  k_deform_main<<<1024, 256, 0, stream>>>(xt, wpk, off2, out);
}

// Round 3
// 93.790 us; speedup vs baseline: 1.4407x; 1.0673x over previous
//
#include <hip/hip_runtime.h>
#include <hip/hip_bf16.h>
#include <stdint.h>

typedef __attribute__((ext_vector_type(8))) short bf16x8;
typedef __attribute__((ext_vector_type(4))) float f32x4;
typedef __attribute__((ext_vector_type(4))) unsigned int u32x4;

__device__ __forceinline__ float u2f(unsigned int u) {
  union { unsigned int i; float f; } c; c.i = u; return c.f;
}
__device__ __forceinline__ unsigned int f2b(float f) {
  union { float f; unsigned int i; } c; c.f = f;
  unsigned int x = c.i;
  return (x + 0x7fffu + ((x >> 16) & 1u)) >> 16;  // RNE to bf16
}

// ================= prep kernel =================
// blocks 0..143    : offset conv + sample-descriptor build  (b,g,kk)
// blocks 144..1167 : transpose x (B,C,H,W) f32 -> xt (B,H,W,C) bf16
// blocks 1168..1423: weight pack -> pre-swizzled bf16 LDS image
__global__ __launch_bounds__(256) void k_prep(
    const float* __restrict__ shape, const float* __restrict__ w_off,
    const float* __restrict__ x, const float* __restrict__ wd,
    u32x4* __restrict__ desc, unsigned short* __restrict__ xt,
    unsigned short* __restrict__ wp) {
  __shared__ float tile[64][65];
  int bid = blockIdx.x;
  int t = threadIdx.x;
  if (bid < 144) {
    // ---- descriptors ----
    int b = bid / 36, rem = bid % 36, g = rem / 9, kk = rem % 9;
    int ky = kk / 3, kx = kk - ky * 3;
    int ocy = g * 18 + kk * 2;
    float wy[18], wx[18];
#pragma unroll
    for (int i = 0; i < 18; ++i) { wy[i] = w_off[ocy * 18 + i]; wx[i] = w_off[(ocy + 1) * 18 + i]; }
    const float* sp = shape + (size_t)b * 2 * 4096;
    u32x4* dp = desc + (size_t)((b * 4 + g) * 9 + kk) * 4096;
    for (int p = t; p < 4096; p += 256) {
      int y = p >> 6, xx0 = p & 63;
      float dy = 0.f, dx = 0.f;
#pragma unroll
      for (int ic = 0; ic < 2; ++ic)
#pragma unroll
        for (int kyy = 0; kyy < 3; ++kyy) {
          int yy = y + kyy - 1;
          if (yy < 0 || yy > 63) continue;
#pragma unroll
          for (int kxx = 0; kxx < 3; ++kxx) {
            int xx = xx0 + kxx - 1;
            if (xx < 0 || xx > 63) continue;
            float sv = sp[ic * 4096 + yy * 64 + xx];
            dy += sv * wy[ic * 9 + kyy * 3 + kxx];
            dx += sv * wx[ic * 9 + kyy * 3 + kxx];
          }
        }
      float sy = dy + (float)(y + ky - 1);
      float sx = dx + (float)(xx0 + kx - 1);
      float fy = floorf(sy), fx = floorf(sx);
      float ly = sy - fy, lx = sx - fx;
      int y0 = (int)fy, x0 = (int)fx;
      float vy0 = (y0 >= 0 && y0 <= 63) ? 1.f : 0.f;
      float vy1 = (y0 >= -1 && y0 <= 62) ? 1.f : 0.f;
      float vx0 = (x0 >= 0 && x0 <= 63) ? 1.f : 0.f;
      float vx1 = (x0 >= -1 && x0 <= 62) ? 1.f : 0.f;
      float w00 = (1.f - ly) * (1.f - lx) * vy0 * vx0;
      float w01 = (1.f - ly) * lx * vy0 * vx1;
      float w10 = ly * (1.f - lx) * vy1 * vx0;
      float w11 = ly * lx * vy1 * vx1;
      unsigned int yc0 = (unsigned int)min(max(y0, 0), 63);
      unsigned int yc1 = (unsigned int)min(max(y0 + 1, 0), 63);
      unsigned int xc0 = (unsigned int)min(max(x0, 0), 63);
      unsigned int xc1 = (unsigned int)min(max(x0 + 1, 0), 63);
      u32x4 d;
      d[0] = f2b(w00) | (f2b(w01) << 16);
      d[1] = f2b(w10) | (f2b(w11) << 16);
      d[2] = yc0 | (yc1 << 8) | (xc0 << 16) | (xc1 << 24);
      d[3] = 0;
      dp[p] = d;
    }
  } else if (bid < 1168) {
    // ---- transpose ----
    int id = bid - 144;                // 1024 = 4b * 4ct * 64pt
    int b = id >> 8, ct = (id >> 6) & 3, pt = id & 63;
    int c0 = ct * 64, p0 = pt * 64;
#pragma unroll
    for (int i = 0; i < 4; ++i) {
      int row = (t >> 4) + i * 16;     // channel-local
      int seg = t & 15;
      float4 v = *(const float4*)&x[(size_t)(b * 256 + c0 + row) * 4096 + p0 + seg * 4];
      tile[row][seg * 4 + 0] = v.x;
      tile[row][seg * 4 + 1] = v.y;
      tile[row][seg * 4 + 2] = v.z;
      tile[row][seg * 4 + 3] = v.w;
    }
    __syncthreads();
    {
      int pl = t >> 2;                 // pos-local 0..63
      int cs = (t & 3) * 16;           // channel-local base
      unsigned int wbuf[8];
#pragma unroll
      for (int j = 0; j < 8; ++j)
        wbuf[j] = f2b(tile[cs + 2 * j][pl]) | (f2b(tile[cs + 2 * j + 1][pl]) << 16);
      unsigned short* dst = xt + (size_t)(b * 4096 + p0 + pl) * 256 + c0 + cs;
      *(u32x4*)(dst) = *(u32x4*)&wbuf[0];
      *(u32x4*)(dst + 8) = *(u32x4*)&wbuf[4];
    }
  } else {
    // ---- weight pack: wp[chunk=kk*4+g][m][c ^ ((m&7)<<3)] = wd[m][g*64+c][kk] ----
    int id = (bid - 1168) * 256 + t;   // 65536 threads: (m, ci)
    int m = id >> 8, ci = id & 255;
    int g = ci >> 6, c = ci & 63;
    int cs = c ^ ((m & 7) << 3);
    const float* src = wd + (size_t)(m * 256 + ci) * 9;
    float v[9];
#pragma unroll
    for (int kk = 0; kk < 9; ++kk) v[kk] = src[kk];
#pragma unroll
    for (int kk = 0; kk < 9; ++kk)
      wp[(size_t)(kk * 4 + g) * 16384 + m * 64 + cs] = (unsigned short)f2b(v[kk]);
  }
}

// ================= main fused kernel =================
// grid 512: (b, y, xh); tile M=256 x N=32, 512 threads (8 waves), K-chunks of 64
// LDS: A dbuf 2x32KB + B dbuf 2x4KB = 72KB -> 2 blocks/CU
#define LOAD_DESC(c, dv) do { \
    dv = descb[(size_t)(((c) & 3) * 9 + ((c) >> 2)) * 4096]; \
  } while (0)

#define ISSUE_CORNERS(c, dv, cv, cw) do { \
    cw[0] = u2f(dv[0] << 16); \
    cw[1] = u2f(dv[0] & 0xffff0000u); \
    cw[2] = u2f(dv[1] << 16); \
    cw[3] = u2f(dv[1] & 0xffff0000u); \
    unsigned int cr = dv[2]; \
    int yc0 = cr & 255, yc1 = (cr >> 8) & 255, xc0 = (cr >> 16) & 255, xc1 = cr >> 24; \
    int chb = ((c) & 3) * 64 + cq * 4; \
    cv[0] = *(const uint2*)(xtb + ((yc0 * 64 + xc0) * 256 + chb)); \
    cv[1] = *(const uint2*)(xtb + ((yc0 * 64 + xc1) * 256 + chb)); \
    cv[2] = *(const uint2*)(xtb + ((yc1 * 64 + xc0) * 256 + chb)); \
    cv[3] = *(const uint2*)(xtb + ((yc1 * 64 + xc1) * 256 + chb)); \
  } while (0)

#define BLEND_WRITE(cv, cw, bbuf) do { \
    float lo0 = 0.f, hi0 = 0.f, lo1 = 0.f, hi1 = 0.f; \
    _Pragma("unroll") for (int cc = 0; cc < 4; ++cc) { \
      unsigned int ux = cv[cc].x, uy = cv[cc].y; \
      lo0 += cw[cc] * u2f(ux << 16); \
      hi0 += cw[cc] * u2f(ux & 0xffff0000u); \
      lo1 += cw[cc] * u2f(uy << 16); \
      hi1 += cw[cc] * u2f(uy & 0xffff0000u); \
    } \
    uint2 o_; \
    o_.x = f2b(lo0) | (f2b(hi0) << 16); \
    o_.y = f2b(lo1) | (f2b(hi1) << 16); \
    *(uint2*)((bbuf) + bwr) = o_; \
  } while (0)

#define STAGE_A(c, abuf) do { \
    const unsigned short* asrc_ = wp + (size_t)(c) * 16384 + t * 8; \
    _Pragma("unroll") for (int i_ = 0; i_ < 4; ++i_) \
      __builtin_amdgcn_global_load_lds( \
          (const __attribute__((address_space(1))) unsigned int*)(asrc_ + i_ * 4096), \
          (__attribute__((address_space(3))) unsigned int*)((abuf) + t * 16 + i_ * 8192), \
          16, 0, 0); \
  } while (0)

#define MFMA_STEP(abuf, bbuf) do { \
    _Pragma("unroll") for (int ks_ = 0; ks_ < 2; ++ks_) { \
      int kb_ = ks_ * 64 + kq; \
      bf16x8 a0_ = *(const bf16x8*)((abuf) + (wid * 32 + lm) * 128 + (kb_ ^ swz)); \
      bf16x8 a1_ = *(const bf16x8*)((abuf) + (wid * 32 + 16 + lm) * 128 + (kb_ ^ swz)); \
      bf16x8 b0_ = *(const bf16x8*)((bbuf) + lm * 128 + (kb_ ^ swz)); \
      bf16x8 b1_ = *(const bf16x8*)((bbuf) + (16 + lm) * 128 + (kb_ ^ swz)); \
      acc00 = __builtin_amdgcn_mfma_f32_16x16x32_bf16(a0_, b0_, acc00, 0, 0, 0); \
      acc01 = __builtin_amdgcn_mfma_f32_16x16x32_bf16(a0_, b1_, acc01, 0, 0, 0); \
      acc10 = __builtin_amdgcn_mfma_f32_16x16x32_bf16(a1_, b0_, acc10, 0, 0, 0); \
      acc11 = __builtin_amdgcn_mfma_f32_16x16x32_bf16(a1_, b1_, acc11, 0, 0, 0); \
    } \
  } while (0)

__global__ __launch_bounds__(512, 4) void k_deform_main(
    const unsigned short* __restrict__ xt, const unsigned short* __restrict__ wp,
    const u32x4* __restrict__ desc, float* __restrict__ out) {
  __shared__ __align__(16) char lds[73728];  // A0,A1: 32KB; B0,B1: 4KB
  const int t = threadIdx.x;
  const int l = t & 63;
  const int wid = t >> 6;

  // XCD-aware chunked swizzle (512 % 8 == 0, bijective)
  int orig = blockIdx.x;
  int bid = (orig & 7) * 64 + (orig >> 3);
  const int xh = bid & 1;
  const int rowid = bid >> 1;        // 0..255
  const int b = rowid >> 6;
  const int y = rowid & 63;

  // sampling map: 16 lanes per position, 4 channels each
  const int p = t >> 4;              // local position 0..31
  const int cq = t & 15;             // channel quad
  const int xg = xh * 32 + p;
  const int bwr = p * 128 + ((cq * 8) ^ ((p & 7) << 4));

  const int lm = l & 15;
  const int kq = (l >> 4) << 4;
  const int swz = (lm & 7) << 4;

  f32x4 acc00 = {}, acc01 = {}, acc10 = {}, acc11 = {};

  const u32x4* descb = desc + (size_t)b * 36 * 4096 + y * 64 + xg;
  const unsigned short* xtb = xt + (size_t)b * 4096 * 256;

  char* ldsA0 = lds;
  char* ldsA1 = lds + 32768;
  char* ldsB0 = lds + 65536;
  char* ldsB1 = lds + 69632;

  uint2 cvX[4], cvY[4];
  float cwX[4], cwY[4];
  u32x4 dvX, dvY;

  // prologue
  {
    u32x4 dv0;
    LOAD_DESC(0, dv0);
    STAGE_A(0, ldsA0);
    ISSUE_CORNERS(0, dv0, cvX, cwX);
    LOAD_DESC(1, dvY);
  }

  for (int pr = 0; pr < 18; ++pr) {
    const int c0 = pr * 2;
    // ---- even chunk: buffers 0 ----
    BLEND_WRITE(cvX, cwX, ldsB0);
    __syncthreads();                  // A[c0] staged + B0 written
    STAGE_A(c0 + 1, ldsA1);
    ISSUE_CORNERS(c0 + 1, dvY, cvY, cwY);
    if (c0 + 2 < 36) LOAD_DESC(c0 + 2, dvX);
    MFMA_STEP(ldsA0, ldsB0);
    // ---- odd chunk: buffers 1 ----
    BLEND_WRITE(cvY, cwY, ldsB1);
    __syncthreads();                  // A[c0+1] staged + B1 written
    if (c0 + 2 < 36) {
      STAGE_A(c0 + 2, ldsA0);
      ISSUE_CORNERS(c0 + 2, dvX, cvX, cwX);
    }
    if (c0 + 3 < 36) LOAD_DESC(c0 + 3, dvY);
    MFMA_STEP(ldsA1, ldsB1);
  }

  // ---- epilogue: ReLU + fp32 store ----
  const int lm4 = (l >> 4) << 2;
  float* ob = out + (size_t)(b * 256 + wid * 32) * 4096 + y * 64 + xh * 32;
#pragma unroll
  for (int r = 0; r < 4; ++r) {
    ob[(size_t)(lm4 + r) * 4096 + lm] = fmaxf(acc00[r], 0.f);
    ob[(size_t)(lm4 + r) * 4096 + 16 + lm] = fmaxf(acc01[r], 0.f);
    ob[(size_t)(16 + lm4 + r) * 4096 + lm] = fmaxf(acc10[r], 0.f);
    ob[(size_t)(16 + lm4 + r) * 4096 + 16 + lm] = fmaxf(acc11[r], 0.f);
  }
}

extern "C" void kernel_launch(void* const* d_in, const int* in_sizes, int n_in,
                              void* d_out, int out_size, void* d_ws, size_t ws_size,
                              hipStream_t stream) {
  const float* x     = (const float*)d_in[0];
  const float* shape = (const float*)d_in[1];
  const float* w_off = (const float*)d_in[2];
  const float* w_def = (const float*)d_in[3];
  float* out = (float*)d_out;
  char* ws = (char*)d_ws;

  u32x4* desc         = (u32x4*)ws;                                   // 9,437,184 B
  unsigned short* xt  = (unsigned short*)(ws + 9437184);              // 8,388,608 B
  unsigned short* wpk = (unsigned short*)(ws + 9437184 + 8388608);    // 1,179,648 B

  k_prep<<<1424, 256, 0, stream>>>(shape, w_off, x, w_def, desc, xt, wpk);
  k_deform_main<<<512, 512, 0, stream>>>(xt, wpk, desc, out);
}

// Round 4
// 78.580 us; speedup vs baseline: 1.7196x; 1.1936x over previous
//
#include <hip/hip_runtime.h>
#include <hip/hip_bf16.h>
#include <stdint.h>

typedef __attribute__((ext_vector_type(8))) short bf16x8;
typedef __attribute__((ext_vector_type(4))) float f32x4;
typedef __attribute__((ext_vector_type(4))) unsigned int u32x4;

__device__ __forceinline__ float u2f(unsigned int u) {
  union { unsigned int i; float f; } c; c.i = u; return c.f;
}
__device__ __forceinline__ unsigned int f2b(float f) {
  union { float f; unsigned int i; } c; c.f = f;
  unsigned int x = c.i;
  return (x + 0x7fffu + ((x >> 16) & 1u)) >> 16;  // RNE to bf16
}

// ================= prep kernel =================
// blocks 0..575    : offset conv + 32B sample-descriptor build (b,g,kk) x 4 bands
// blocks 576..1599 : transpose x (B,C,H,W) f32 -> xt (B,H,W,C) bf16
// blocks 1600..1855: weight pack -> pre-swizzled bf16 LDS image
__global__ __launch_bounds__(256) void k_prep(
    const float* __restrict__ shape, const float* __restrict__ w_off,
    const float* __restrict__ x, const float* __restrict__ wd,
    char* __restrict__ desc, unsigned short* __restrict__ xt,
    unsigned short* __restrict__ wp) {
  __shared__ float tile[64][65];
  int bid = blockIdx.x;
  int t = threadIdx.x;
  if (bid < 576) {
    // ---- descriptors: record = {u32 off[4] (byte offsets into xt image, g folded),
    //                             u32 wpack01, u32 wpack23, pad, pad} ----
    int band = bid & 3;
    int rem = bid >> 2;                 // = b*36 + g*9 + kk  (record-major chunk id)
    int b = rem / 36, r2 = rem % 36, g = r2 / 9, kk = r2 % 9;
    int ky = kk / 3, kx = kk - ky * 3;
    int ocy = g * 18 + kk * 2;
    float wy[18], wx[18];
#pragma unroll
    for (int i = 0; i < 18; ++i) { wy[i] = w_off[ocy * 18 + i]; wx[i] = w_off[(ocy + 1) * 18 + i]; }
    const float* sp = shape + (size_t)b * 2 * 4096;
    char* dp = desc + (size_t)rem * 4096 * 32;
#pragma unroll
    for (int e = 0; e < 4; ++e) {
      int p = band * 1024 + t * 4 + e;
      int y = p >> 6, xx0 = p & 63;
      float dy = 0.f, dx = 0.f;
#pragma unroll
      for (int ic = 0; ic < 2; ++ic)
#pragma unroll
        for (int kyy = 0; kyy < 3; ++kyy) {
          int yy = y + kyy - 1;
          if (yy < 0 || yy > 63) continue;
#pragma unroll
          for (int kxx = 0; kxx < 3; ++kxx) {
            int xx = xx0 + kxx - 1;
            if (xx < 0 || xx > 63) continue;
            float sv = sp[ic * 4096 + yy * 64 + xx];
            dy += sv * wy[ic * 9 + kyy * 3 + kxx];
            dx += sv * wx[ic * 9 + kyy * 3 + kxx];
          }
        }
      float sy = dy + (float)(y + ky - 1);
      float sx = dx + (float)(xx0 + kx - 1);
      float fy = floorf(sy), fx = floorf(sx);
      float ly = sy - fy, lx = sx - fx;
      int y0 = (int)fy, x0 = (int)fx;
      float vy0 = (y0 >= 0 && y0 <= 63) ? 1.f : 0.f;
      float vy1 = (y0 >= -1 && y0 <= 62) ? 1.f : 0.f;
      float vx0 = (x0 >= 0 && x0 <= 63) ? 1.f : 0.f;
      float vx1 = (x0 >= -1 && x0 <= 62) ? 1.f : 0.f;
      float w00 = (1.f - ly) * (1.f - lx) * vy0 * vx0;
      float w01 = (1.f - ly) * lx * vy0 * vx1;
      float w10 = ly * (1.f - lx) * vy1 * vx0;
      float w11 = ly * lx * vy1 * vx1;
      unsigned int yc0 = (unsigned int)min(max(y0, 0), 63);
      unsigned int yc1 = (unsigned int)min(max(y0 + 1, 0), 63);
      unsigned int xc0 = (unsigned int)min(max(x0, 0), 63);
      unsigned int xc1 = (unsigned int)min(max(x0 + 1, 0), 63);
      unsigned int gb = (unsigned int)(g * 128);   // g*64 elements in bytes
      u32x4 offs;
      offs[0] = (yc0 * 64 + xc0) * 512 + gb;
      offs[1] = (yc0 * 64 + xc1) * 512 + gb;
      offs[2] = (yc1 * 64 + xc0) * 512 + gb;
      offs[3] = (yc1 * 64 + xc1) * 512 + gb;
      uint2 wpk;
      wpk.x = f2b(w00) | (f2b(w01) << 16);
      wpk.y = f2b(w10) | (f2b(w11) << 16);
      char* r = dp + (size_t)p * 32;
      *(u32x4*)(r) = offs;
      *(uint2*)(r + 16) = wpk;
    }
  } else if (bid < 1600) {
    // ---- transpose ----
    int id = bid - 576;                 // 1024 = 4b * 4ct * 64pt
    int b = id >> 8, ct = (id >> 6) & 3, pt = id & 63;
    int c0 = ct * 64, p0 = pt * 64;
#pragma unroll
    for (int i = 0; i < 4; ++i) {
      int row = (t >> 4) + i * 16;
      int seg = t & 15;
      float4 v = *(const float4*)&x[(size_t)(b * 256 + c0 + row) * 4096 + p0 + seg * 4];
      tile[row][seg * 4 + 0] = v.x;
      tile[row][seg * 4 + 1] = v.y;
      tile[row][seg * 4 + 2] = v.z;
      tile[row][seg * 4 + 3] = v.w;
    }
    __syncthreads();
    {
      int pl = t >> 2;
      int cs = (t & 3) * 16;
      unsigned int wbuf[8];
#pragma unroll
      for (int j = 0; j < 8; ++j)
        wbuf[j] = f2b(tile[cs + 2 * j][pl]) | (f2b(tile[cs + 2 * j + 1][pl]) << 16);
      unsigned short* dst = xt + (size_t)(b * 4096 + p0 + pl) * 256 + c0 + cs;
      *(u32x4*)(dst) = *(u32x4*)&wbuf[0];
      *(u32x4*)(dst + 8) = *(u32x4*)&wbuf[4];
    }
  } else {
    // ---- weight pack: wp[chunk=kk*4+g][m][c ^ ((m&7)<<3)] = wd[m][g*64+c][kk] ----
    int id = (bid - 1600) * 256 + t;
    int m = id >> 8, ci = id & 255;
    int g = ci >> 6, c = ci & 63;
    int cs = c ^ ((m & 7) << 3);
    const float* src = wd + (size_t)(m * 256 + ci) * 9;
    float v[9];
#pragma unroll
    for (int kk = 0; kk < 9; ++kk) v[kk] = src[kk];
#pragma unroll
    for (int kk = 0; kk < 9; ++kk)
      wp[(size_t)(kk * 4 + g) * 16384 + m * 64 + cs] = (unsigned short)f2b(v[kk]);
  }
}

// ================= main fused kernel =================
// grid 512: (b, y, xh); tile M=256 x N=32, 512 threads (8 waves), K-chunks of 64
// Counted-vmcnt phase schedule: per phase issues STAGE(4)+CORNERS(4)+DESC(2) vmem;
// pre-barrier s_waitcnt vmcnt(6) drains only STAGE; corners+desc fly across barriers.
struct CSet { uint2 v0, v1, v2, v3; uint2 w; };

#define DESC_LD(c, dvo, dvw) do { \
    const char* rp_ = descb + (size_t)((((c) & 3) * 9 + ((c) >> 2))) * (4096 * 32); \
    dvo = *(const u32x4*)(rp_); \
    dvw = *(const uint2*)(rp_ + 16); \
  } while (0)

#define CORNERS(S, dvo, dvw) do { \
    (S).v0 = *(const uint2*)(xtbB + (dvo)[0] + cb16); \
    (S).v1 = *(const uint2*)(xtbB + (dvo)[1] + cb16); \
    (S).v2 = *(const uint2*)(xtbB + (dvo)[2] + cb16); \
    (S).v3 = *(const uint2*)(xtbB + (dvo)[3] + cb16); \
    (S).w = (dvw); \
  } while (0)

#define BLEND(S, bbuf) do { \
    float w0_ = u2f((S).w.x << 16), w1_ = u2f((S).w.x & 0xffff0000u); \
    float w2_ = u2f((S).w.y << 16), w3_ = u2f((S).w.y & 0xffff0000u); \
    float lo0 = 0.f, hi0 = 0.f, lo1 = 0.f, hi1 = 0.f; \
    lo0 += w0_ * u2f((S).v0.x << 16); hi0 += w0_ * u2f((S).v0.x & 0xffff0000u); \
    lo1 += w0_ * u2f((S).v0.y << 16); hi1 += w0_ * u2f((S).v0.y & 0xffff0000u); \
    lo0 += w1_ * u2f((S).v1.x << 16); hi0 += w1_ * u2f((S).v1.x & 0xffff0000u); \
    lo1 += w1_ * u2f((S).v1.y << 16); hi1 += w1_ * u2f((S).v1.y & 0xffff0000u); \
    lo0 += w2_ * u2f((S).v2.x << 16); hi0 += w2_ * u2f((S).v2.x & 0xffff0000u); \
    lo1 += w2_ * u2f((S).v2.y << 16); hi1 += w2_ * u2f((S).v2.y & 0xffff0000u); \
    lo0 += w3_ * u2f((S).v3.x << 16); hi0 += w3_ * u2f((S).v3.x & 0xffff0000u); \
    lo1 += w3_ * u2f((S).v3.y << 16); hi1 += w3_ * u2f((S).v3.y & 0xffff0000u); \
    uint2 o_; \
    o_.x = f2b(lo0) | (f2b(hi0) << 16); \
    o_.y = f2b(lo1) | (f2b(hi1) << 16); \
    *(uint2*)((bbuf) + bwr) = o_; \
  } while (0)

#define STAGE_A(c, abuf) do { \
    const unsigned short* asrc_ = wp + (size_t)(c) * 16384 + t * 8; \
    _Pragma("unroll") for (int i_ = 0; i_ < 4; ++i_) \
      __builtin_amdgcn_global_load_lds( \
          (const __attribute__((address_space(1))) unsigned int*)(asrc_ + i_ * 4096), \
          (__attribute__((address_space(3))) unsigned int*)((abuf) + t * 16 + i_ * 8192), \
          16, 0, 0); \
  } while (0)

#define MFMA_STEP(abuf, bbuf) do { \
    _Pragma("unroll") for (int ks_ = 0; ks_ < 2; ++ks_) { \
      int kb_ = ks_ * 64 + kq; \
      bf16x8 a0_ = *(const bf16x8*)((abuf) + (wid * 32 + lm) * 128 + (kb_ ^ swz)); \
      bf16x8 a1_ = *(const bf16x8*)((abuf) + (wid * 32 + 16 + lm) * 128 + (kb_ ^ swz)); \
      bf16x8 b0_ = *(const bf16x8*)((bbuf) + lm * 128 + (kb_ ^ swz)); \
      bf16x8 b1_ = *(const bf16x8*)((bbuf) + (16 + lm) * 128 + (kb_ ^ swz)); \
      acc00 = __builtin_amdgcn_mfma_f32_16x16x32_bf16(a0_, b0_, acc00, 0, 0, 0); \
      acc01 = __builtin_amdgcn_mfma_f32_16x16x32_bf16(a0_, b1_, acc01, 0, 0, 0); \
      acc10 = __builtin_amdgcn_mfma_f32_16x16x32_bf16(a1_, b0_, acc10, 0, 0, 0); \
      acc11 = __builtin_amdgcn_mfma_f32_16x16x32_bf16(a1_, b1_, acc11, 0, 0, 0); \
    } \
  } while (0)

// Phase for chunk c: consume A(c),B(c); stage A(c+1); issue corners(c+2); load desc(c+3);
// blend corners(c+1) -> B(c+1). Indices clamped so vmem counts are phase-invariant.
#define PHASE(c, Acur, Anext, Bnext, Sfill, Sblend, dvoF, dvwF, dvoU, dvwU) do { \
    int cs_ = (c) + 1 < 36 ? (c) + 1 : 35; \
    int cd_ = (c) + 3 < 36 ? (c) + 3 : 35; \
    STAGE_A(cs_, Anext); \
    CORNERS(Sfill, dvoU, dvwU); \
    DESC_LD(cd_, dvoF, dvwF); \
    MFMA_STEP(Acur, (Bnext) == ldsB0 ? ldsB1 : ldsB0); \
    BLEND(Sblend, Bnext); \
    asm volatile("s_waitcnt lgkmcnt(0)" ::: "memory"); \
    asm volatile("s_waitcnt vmcnt(6)" ::: "memory"); \
    __builtin_amdgcn_s_barrier(); \
  } while (0)

__global__ __launch_bounds__(512, 4) void k_deform_main(
    const unsigned short* __restrict__ xt, const unsigned short* __restrict__ wp,
    const char* __restrict__ desc, float* __restrict__ out) {
  __shared__ __align__(16) char lds[73728];  // A0,A1: 32KB; B0,B1: 4KB
  const int t = threadIdx.x;
  const int l = t & 63;
  const int wid = t >> 6;

  int orig = blockIdx.x;
  int bid = (orig & 7) * 64 + (orig >> 3);   // XCD chunked swizzle (512%8==0)
  const int xh = bid & 1;
  const int rowid = bid >> 1;
  const int b = rowid >> 6;
  const int y = rowid & 63;

  const int p = t >> 4;              // local position 0..31
  const int cq = t & 15;             // channel quad
  const int xg = xh * 32 + p;
  const int cb16 = cq * 8;           // channel byte offset within group row
  const int bwr = p * 128 + ((cq * 8) ^ ((p & 7) << 4));

  const int lm = l & 15;
  const int kq = (l >> 4) << 4;
  const int swz = (lm & 7) << 4;

  f32x4 acc00 = {}, acc01 = {}, acc10 = {}, acc11 = {};

  const char* descb = desc + (size_t)(b * 36 * 4096 + y * 64 + xg) * 32;
  const char* xtbB = (const char*)(xt + (size_t)b * 4096 * 256);

  char* ldsA0 = lds;
  char* ldsA1 = lds + 32768;
  char* ldsB0 = lds + 65536;
  char* ldsB1 = lds + 69632;

  CSet SE, SO;
  u32x4 dvoE, dvoO;
  uint2 dvwE, dvwO;

  // ---- prologue: B(0) built, A(0) staged+drained, corners(1) in flight, desc(2) loaded ----
  {
    u32x4 o0, o1; uint2 w0p, w1p;
    DESC_LD(0, o0, w0p);
    DESC_LD(1, o1, w1p);
    DESC_LD(2, dvoO, dvwO);
    STAGE_A(0, ldsA0);
    CSet S0;
    CORNERS(S0, o0, w0p);
    CORNERS(SO, o1, w1p);
    BLEND(S0, ldsB0);
    asm volatile("s_waitcnt lgkmcnt(0)" ::: "memory");
    asm volatile("s_waitcnt vmcnt(4)" ::: "memory");   // drain STAGE_A(0); corners(1) stay
    __builtin_amdgcn_s_barrier();
  }

  for (int pr = 0; pr < 18; ++pr) {
    const int c0 = pr * 2;
    PHASE(c0,     ldsA0, ldsA1, ldsB1, SE, SO, dvoE, dvwE, dvoO, dvwO);
    PHASE(c0 + 1, ldsA1, ldsA0, ldsB0, SO, SE, dvoO, dvwO, dvoE, dvwE);
  }

  // ---- epilogue: ReLU + fp32 store ----
  const int lm4 = (l >> 4) << 2;
  float* ob = out + (size_t)(b * 256 + wid * 32) * 4096 + y * 64 + xh * 32;
#pragma unroll
  for (int r = 0; r < 4; ++r) {
    ob[(size_t)(lm4 + r) * 4096 + lm] = fmaxf(acc00[r], 0.f);
    ob[(size_t)(lm4 + r) * 4096 + 16 + lm] = fmaxf(acc01[r], 0.f);
    ob[(size_t)(16 + lm4 + r) * 4096 + lm] = fmaxf(acc10[r], 0.f);
    ob[(size_t)(16 + lm4 + r) * 4096 + 16 + lm] = fmaxf(acc11[r], 0.f);
  }
}

extern "C" void kernel_launch(void* const* d_in, const int* in_sizes, int n_in,
                              void* d_out, int out_size, void* d_ws, size_t ws_size,
                              hipStream_t stream) {
  const float* x     = (const float*)d_in[0];
  const float* shape = (const float*)d_in[1];
  const float* w_off = (const float*)d_in[2];
  const float* w_def = (const float*)d_in[3];
  float* out = (float*)d_out;
  char* ws = (char*)d_ws;

  char* desc          = ws;                                           // 18,874,368 B
  unsigned short* xt  = (unsigned short*)(ws + 18874368);             //  8,388,608 B
  unsigned short* wpk = (unsigned short*)(ws + 18874368 + 8388608);   //  1,179,648 B

  k_prep<<<1856, 256, 0, stream>>>(shape, w_off, x, w_def, desc, xt, wpk);
  k_deform_main<<<512, 512, 0, stream>>>(xt, wpk, desc, out);
}